// Round 6
// baseline (602.436 us; speedup 1.0000x reference)
//
#include <hip/hip_runtime.h>
#include <math.h>

#define B_      2
#define N_      4096
#define H_      1024
#define HEADS_  16
#define DH_     64
#define M_      256
#define NSPLIT  16
#define CE      65   // ctx rows: e 0..63 = context, 64 = k_cumsum
#define NT      8192 // B_*N_ tokens (Vt row stride)

constexpr float NORMALIZER = 0.35355339059327373f; // 64^-0.25
constexpr float RATIO      = 0.0625f;              // 256^-0.5
constexpr float KEPS       = 1e-3f;

typedef __bf16 bf16x8 __attribute__((ext_vector_type(8)));
typedef __bf16 bf16x4 __attribute__((ext_vector_type(4)));
typedef float  f32x4  __attribute__((ext_vector_type(4)));

__device__ inline bf16x4 shfl4(bf16x4 v, int src) {
    union { bf16x4 b; int i[2]; } u;
    u.b = v;
    u.i[0] = __shfl(u.i[0], src);
    u.i[1] = __shfl(u.i[1], src);
    return u.b;
}
__device__ inline bf16x8 cat44(bf16x4 a, bf16x4 b) {
    bf16x8 r;
#pragma unroll
    for (int i = 0; i < 4; ++i) { r[i] = a[i]; r[i + 4] = b[i]; }
    return r;
}

// ======================================================================
// Split fp32 -> bf16 (hi, lo)
// ======================================================================
__global__ __launch_bounds__(256) void split_bf16(
    const float* __restrict__ src, __bf16* __restrict__ hi, __bf16* __restrict__ lo)
{
    int i = blockIdx.x * 256 + threadIdx.x;
    float4 v = ((const float4*)src)[i];
    float vv[4] = {v.x, v.y, v.z, v.w};
    bf16x4 h, l;
#pragma unroll
    for (int j = 0; j < 4; ++j) {
        __bf16 hh = (__bf16)vv[j];
        h[j] = hh;
        l[j] = (__bf16)(vv[j] - (float)hh);
    }
    ((bf16x4*)hi)[i] = h;
    ((bf16x4*)lo)[i] = l;
}

__global__ __launch_bounds__(256) void split_w(
    const float* __restrict__ W0, const float* __restrict__ W1,
    const float* __restrict__ W2, const float* __restrict__ W3,
    __bf16* __restrict__ hi, __bf16* __restrict__ lo)
{
    const float* src = W0;
    if (blockIdx.y == 1) src = W1;
    else if (blockIdx.y == 2) src = W2;
    else if (blockIdx.y == 3) src = W3;
    int i = blockIdx.x * 256 + threadIdx.x;
    size_t o = (size_t)blockIdx.y * 262144 + i;
    float4 v = ((const float4*)src)[i];
    float vv[4] = {v.x, v.y, v.z, v.w};
    bf16x4 h, l;
#pragma unroll
    for (int j = 0; j < 4; ++j) {
        __bf16 hh = (__bf16)vv[j];
        h[j] = hh;
        l[j] = (__bf16)(vv[j] - (float)hh);
    }
    ((bf16x4*)hi)[o] = h;
    ((bf16x4*)lo)[o] = l;
}

// ======================================================================
// Split-bf16 MFMA GEMM, C = A@W^T + bias.
// BF16OUT: write C as bf16 hi/lo. VTZ2: z==2 output written transposed
// Vt[col][token] (col = h*64+d, token = b*4096+n) for LDS-free ctx kernel.
// ======================================================================
template<bool BF16OUT, bool VTZ2>
__global__ __launch_bounds__(256, 2) void gemm_mfma3(
    const __bf16* __restrict__ Ah, const __bf16* __restrict__ Al,
    const __bf16* __restrict__ Bh0, const __bf16* __restrict__ Bl0,
    const __bf16* __restrict__ Bh1, const __bf16* __restrict__ Bl1,
    const __bf16* __restrict__ Bh2, const __bf16* __restrict__ Bl2,
    const float* __restrict__ bi0, const float* __restrict__ bi1, const float* __restrict__ bi2,
    float* __restrict__ C0,
    __bf16* __restrict__ Ch0, __bf16* __restrict__ Cl0,
    __bf16* __restrict__ Ch1, __bf16* __restrict__ Cl1,
    __bf16* __restrict__ Ch2, __bf16* __restrict__ Cl2)
{
    const __bf16* Bh = Bh0; const __bf16* Bl = Bl0; const float* bias = bi0;
    __bf16* Ch = Ch0; __bf16* Cl = Cl0;
    if (blockIdx.z == 1) { Bh = Bh1; Bl = Bl1; bias = bi1; Ch = Ch1; Cl = Cl1; }
    else if (blockIdx.z == 2) { Bh = Bh2; Bl = Bl2; bias = bi2; Ch = Ch2; Cl = Cl2; }

    __shared__ alignas(16) __bf16 AhS[128][40];
    __shared__ alignas(16) __bf16 AlS[128][40];
    __shared__ alignas(16) __bf16 BhS[128][40];
    __shared__ alignas(16) __bf16 BlS[128][40];

    const int t    = threadIdx.x;
    const int lane = t & 63;
    const int lm   = lane & 15;
    const int lq   = lane >> 4;
    const int wave = t >> 6;
    const int wm   = (wave >> 1) * 64;
    const int wn   = (wave & 1) * 64;
    const int m0   = blockIdx.y * 128;
    const int n0   = blockIdx.x * 128;
    const int K    = 1024;

    f32x4 acc[4][4];
#pragma unroll
    for (int i = 0; i < 4; ++i)
#pragma unroll
        for (int j = 0; j < 4; ++j) acc[i][j] = (f32x4){0.f, 0.f, 0.f, 0.f};

    for (int k0 = 0; k0 < K; k0 += 32) {
        __syncthreads();
#pragma unroll
        for (int i = 0; i < 2; ++i) {
            int idx = i * 256 + t;
            int row = idx >> 2;
            int c8  = (idx & 3) * 8;
            size_t ga = (size_t)(m0 + row) * K + k0 + c8;
            size_t gb = (size_t)(n0 + row) * K + k0 + c8;
            *(float4*)&AhS[row][c8] = *(const float4*)(Ah + ga);
            *(float4*)&AlS[row][c8] = *(const float4*)(Al + ga);
            *(float4*)&BhS[row][c8] = *(const float4*)(Bh + gb);
            *(float4*)&BlS[row][c8] = *(const float4*)(Bl + gb);
        }
        __syncthreads();

        bf16x8 bh[4], bl[4];
#pragma unroll
        for (int j = 0; j < 4; ++j) {
            bh[j] = *(const bf16x8*)&BhS[wn + j * 16 + lm][lq * 8];
            bl[j] = *(const bf16x8*)&BlS[wn + j * 16 + lm][lq * 8];
        }
#pragma unroll
        for (int i = 0; i < 4; ++i) {
            bf16x8 ah = *(const bf16x8*)&AhS[wm + i * 16 + lm][lq * 8];
            bf16x8 al = *(const bf16x8*)&AlS[wm + i * 16 + lm][lq * 8];
#pragma unroll
            for (int j = 0; j < 4; ++j) {
                acc[i][j] = __builtin_amdgcn_mfma_f32_16x16x32_bf16(ah, bh[j], acc[i][j], 0, 0, 0);
                acc[i][j] = __builtin_amdgcn_mfma_f32_16x16x32_bf16(al, bh[j], acc[i][j], 0, 0, 0);
                acc[i][j] = __builtin_amdgcn_mfma_f32_16x16x32_bf16(ah, bl[j], acc[i][j], 0, 0, 0);
            }
        }
    }

    float bsr[4];
#pragma unroll
    for (int j = 0; j < 4; ++j) bsr[j] = bias[n0 + wn + j * 16 + lm];

    if (VTZ2 && blockIdx.z == 2) {
        // transposed store: Vt[col][token], 4 consecutive tokens per lane (bf16x4)
#pragma unroll
        for (int i = 0; i < 4; ++i)
#pragma unroll
            for (int j = 0; j < 4; ++j) {
                int col  = n0 + wn + j * 16 + lm;
                int rowm = m0 + wm + i * 16 + lq * 4;
                bf16x4 oh, ol;
#pragma unroll
                for (int r = 0; r < 4; ++r) {
                    float o = acc[i][j][r] + bsr[j];
                    __bf16 hh = (__bf16)o;
                    oh[r] = hh;
                    ol[r] = (__bf16)(o - (float)hh);
                }
                size_t oa = (size_t)col * NT + rowm;
                *(bf16x4*)(Ch + oa) = oh;
                *(bf16x4*)(Cl + oa) = ol;
            }
    } else {
#pragma unroll
        for (int i = 0; i < 4; ++i)
#pragma unroll
            for (int r = 0; r < 4; ++r) {
                int rowm = m0 + wm + i * 16 + lq * 4 + r;
#pragma unroll
                for (int j = 0; j < 4; ++j) {
                    int col = n0 + wn + j * 16 + lm;
                    float o = acc[i][j][r] + bsr[j];
                    if (BF16OUT) {
                        __bf16 hh = (__bf16)o;
                        Ch[(size_t)rowm * 1024 + col] = hh;
                        Cl[(size_t)rowm * 1024 + col] = (__bf16)(o - (float)hh);
                    } else {
                        C0[(size_t)rowm * 1024 + col] = o;
                    }
                }
            }
    }
}

// ======================================================================
// diag_k from bf16 hi/lo K
// ======================================================================
__global__ __launch_bounds__(256) void diag_kernel(
    const __bf16* __restrict__ Kh, const __bf16* __restrict__ Kl,
    float* __restrict__ diag, float* __restrict__ partials)
{
    int gt = blockIdx.x * 256 + threadIdx.x;
    int r  = gt >> 2;
    int q  = gt & 3;
    const bf16x8* ph = (const bf16x8*)(Kh + (size_t)r * 64 + q * 16);
    const bf16x8* pl = (const bf16x8*)(Kl + (size_t)r * 64 + q * 16);
    float s = 0.f;
#pragma unroll
    for (int i = 0; i < 2; ++i) {
        bf16x8 vh = ph[i], vl = pl[i];
#pragma unroll
        for (int j = 0; j < 8; ++j) {
            float x = (float)vh[j] + (float)vl[j];
            s += x * x;
        }
    }
    s += __shfl_xor(s, 1);
    s += __shfl_xor(s, 2);
    float d = -0.5f * s;
    if (q == 0) {
        int h = r & 15, bn = r >> 4;
        int n = bn & 4095, b = bn >> 12;
        diag[(((size_t)b * 16 + h) << 12) + n] = d;
    }
    __shared__ float red[256];
    red[threadIdx.x] = d;
    __syncthreads();
    for (int s2 = 128; s2 > 0; s2 >>= 1) {
        if (threadIdx.x < s2) red[threadIdx.x] = fmaxf(red[threadIdx.x], red[threadIdx.x + s2]);
        __syncthreads();
    }
    if (threadIdx.x == 0) partials[blockIdx.x] = red[0];
}

__global__ __launch_bounds__(256) void reduce_stab(
    const float* __restrict__ partials, float* __restrict__ stab, int n)
{
    float m = -3.0e38f;
    for (int i = threadIdx.x; i < n; i += 256) m = fmaxf(m, partials[i]);
    __shared__ float red[256];
    red[threadIdx.x] = m;
    __syncthreads();
    for (int s2 = 128; s2 > 0; s2 >>= 1) {
        if (threadIdx.x < s2) red[threadIdx.x] = fmaxf(red[threadIdx.x], red[threadIdx.x + s2]);
        __syncthreads();
    }
    if (threadIdx.x == 0) stab[0] = red[0];
}

// ======================================================================
// ctx via MFMA, ZERO LDS. grid (NSPLIT, 2, 32). 4 waves, wave owns 32 m.
// dash D[n][m] via MFMA (K global, proj reg-cached); exp in regs;
// kf C->A layout via 2-source-lane shfl (same verified pattern as out_mfma);
// B-operand = Vt[e][token] from global (16B contiguous per lane).
// kcs in registers. Epilogue: direct f32x4 stores to ctxp (no LDS).
// ======================================================================
__global__ __launch_bounds__(256, 2) void ctx_mfma(
    const __bf16* __restrict__ Kh, const __bf16* __restrict__ Kl,
    const __bf16* __restrict__ Vth, const __bf16* __restrict__ Vtl,
    const __bf16* __restrict__ projH, const __bf16* __restrict__ projL,
    const float* __restrict__ diag, const float* __restrict__ stabp,
    float* __restrict__ ctxp)
{
    const int t    = threadIdx.x;
    const int lane = t & 63;
    const int w    = t >> 6;
    const int lm   = lane & 15;
    const int lq   = lane >> 4;
    const int bh   = blockIdx.z;
    const int b    = bh >> 4, h = bh & 15;
    const int mh   = blockIdx.y;
    const int slice = blockIdx.x;
    const float stab = stabp[0];
    const size_t rowbase = (size_t)b * N_ * H_ + (size_t)h * DH_;
    const size_t vtbase  = (size_t)h * DH_ * NT + (size_t)b * N_;
    const float* diag_bh = diag + (size_t)bh * N_;

    // proj B-frags, register-cached
    bf16x8 ph[2][2], pl[2][2];
#pragma unroll
    for (int mf = 0; mf < 2; ++mf)
#pragma unroll
        for (int ks = 0; ks < 2; ++ks) {
            size_t pa = (size_t)(mh * 128 + w * 32 + mf * 16 + lm) * 64 + ks * 32 + lq * 8;
            ph[mf][ks] = *(const bf16x8*)(projH + pa);
            pl[mf][ks] = *(const bf16x8*)(projL + pa);
        }

    f32x4 acc[2][4];
#pragma unroll
    for (int mf = 0; mf < 2; ++mf)
#pragma unroll
        for (int ef = 0; ef < 4; ++ef) acc[mf][ef] = (f32x4){0.f, 0.f, 0.f, 0.f};
    float accK[2] = {0.f, 0.f};

    for (int tile = 0; tile < 4; ++tile) {
        const int n0 = slice * (N_ / NSPLIT) + tile * 64;

        // dash MFMA: D[n][m], A = K rows (global), B = proj (regs)
        f32x4 dsh[4][2];
#pragma unroll
        for (int nf = 0; nf < 4; ++nf) {
#pragma unroll
            for (int mf = 0; mf < 2; ++mf) dsh[nf][mf] = (f32x4){0.f, 0.f, 0.f, 0.f};
            bf16x8 ah[2], al[2];
#pragma unroll
            for (int ks = 0; ks < 2; ++ks) {
                size_t ka = rowbase + (size_t)(n0 + nf * 16 + lm) * H_ + ks * 32 + lq * 8;
                ah[ks] = *(const bf16x8*)(Kh + ka);
                al[ks] = *(const bf16x8*)(Kl + ka);
            }
#pragma unroll
            for (int mf = 0; mf < 2; ++mf)
#pragma unroll
                for (int ks = 0; ks < 2; ++ks) {
                    dsh[nf][mf] = __builtin_amdgcn_mfma_f32_16x16x32_bf16(ah[ks], ph[mf][ks], dsh[nf][mf], 0, 0, 0);
                    dsh[nf][mf] = __builtin_amdgcn_mfma_f32_16x16x32_bf16(al[ks], ph[mf][ks], dsh[nf][mf], 0, 0, 0);
                    dsh[nf][mf] = __builtin_amdgcn_mfma_f32_16x16x32_bf16(ah[ks], pl[mf][ks], dsh[nf][mf], 0, 0, 0);
                }
        }

        // exp -> kf split into regs (lane: m = mwave+mf*16+lm, n = nf*16+lq*4+r)
        bf16x4 vh[4][2], vl[4][2];
#pragma unroll
        for (int nf = 0; nf < 4; ++nf) {
            float4 dgv = *(const float4*)(diag_bh + n0 + nf * 16 + lq * 4);
            float dga[4] = {dgv.x, dgv.y, dgv.z, dgv.w};
#pragma unroll
            for (int mf = 0; mf < 2; ++mf) {
#pragma unroll
                for (int r = 0; r < 4; ++r) {
                    float kf = RATIO * (__expf((dga[r] - stab) + NORMALIZER * dsh[nf][mf][r]) + KEPS);
                    accK[mf] += kf;
                    __bf16 hh = (__bf16)kf;
                    vh[nf][mf][r] = hh;
                    vl[nf][mf][r] = (__bf16)(kf - (float)hh);
                }
            }
        }

        // ctx MFMA: A-frags via shfl (dest needs nf=2ks+(lq>>1) from 2 source lanes),
        // B-frags from Vt global.
#pragma unroll
        for (int ks = 0; ks < 2; ++ks) {
            int s0 = ((2 * lq + 0) & 3) * 16 + lm;
            int s1 = ((2 * lq + 1) & 3) * 16 + lm;
            bf16x8 afh[2], afl[2];
#pragma unroll
            for (int mf = 0; mf < 2; ++mf) {
                bf16x4 aH0 = shfl4(vh[2 * ks + 0][mf], s0);
                bf16x4 aH1 = shfl4(vh[2 * ks + 0][mf], s1);
                bf16x4 bH0 = shfl4(vh[2 * ks + 1][mf], s0);
                bf16x4 bH1 = shfl4(vh[2 * ks + 1][mf], s1);
                bf16x4 aL0 = shfl4(vl[2 * ks + 0][mf], s0);
                bf16x4 aL1 = shfl4(vl[2 * ks + 0][mf], s1);
                bf16x4 bL0 = shfl4(vl[2 * ks + 1][mf], s0);
                bf16x4 bL1 = shfl4(vl[2 * ks + 1][mf], s1);
                afh[mf] = (lq & 2) ? cat44(bH0, bH1) : cat44(aH0, aH1);
                afl[mf] = (lq & 2) ? cat44(bL0, bL1) : cat44(aL0, aL1);
            }
#pragma unroll
            for (int ef = 0; ef < 4; ++ef) {
                size_t va = vtbase + (size_t)(ef * 16 + lm) * NT + n0 + ks * 32 + lq * 8;
                bf16x8 bfh = *(const bf16x8*)(Vth + va);
                bf16x8 bfl = *(const bf16x8*)(Vtl + va);
#pragma unroll
                for (int mf = 0; mf < 2; ++mf) {
                    acc[mf][ef] = __builtin_amdgcn_mfma_f32_16x16x32_bf16(afh[mf], bfh, acc[mf][ef], 0, 0, 0);
                    acc[mf][ef] = __builtin_amdgcn_mfma_f32_16x16x32_bf16(afl[mf], bfh, acc[mf][ef], 0, 0, 0);
                    acc[mf][ef] = __builtin_amdgcn_mfma_f32_16x16x32_bf16(afh[mf], bfl, acc[mf][ef], 0, 0, 0);
                }
            }
        }
    }

    // kcs: reduce over lq groups (n-quads); lane (lq==0) holds m = mf*16+lm sum
#pragma unroll
    for (int mf = 0; mf < 2; ++mf) {
        accK[mf] += __shfl_xor(accK[mf], 16);
        accK[mf] += __shfl_xor(accK[mf], 32);
    }

    // epilogue: direct stores. acc C-layout: col = e = ef*16+lm, row = m-quad lq*4+r.
    const size_t obase = ((size_t)slice * (B_ * HEADS_) + bh) * (CE * M_);
#pragma unroll
    for (int mf = 0; mf < 2; ++mf) {
#pragma unroll
        for (int ef = 0; ef < 4; ++ef) {
            size_t oa = obase + (size_t)(ef * 16 + lm) * M_ + mh * 128 + w * 32 + mf * 16 + lq * 4;
            *(f32x4*)(ctxp + oa) = acc[mf][ef];
        }
        if (lq == 0)
            ctxp[obase + (size_t)64 * M_ + mh * 128 + w * 32 + mf * 16 + lm] = accK[mf];
    }
}

// ======================================================================
// Reduce ctx partials over slices -> bf16 hi/lo ctxT[bh][e][m]
// ======================================================================
__global__ __launch_bounds__(256) void ctx_reduce(
    const float* __restrict__ ctxp, __bf16* __restrict__ ctxTh, __bf16* __restrict__ ctxTl)
{
    int idx = blockIdx.x * 256 + threadIdx.x;     // [0, 32*65*256)
    const size_t SLICE = (size_t)(B_ * HEADS_) * CE * M_;
    float s = 0.f;
#pragma unroll
    for (int k = 0; k < NSPLIT; ++k) s += ctxp[(size_t)k * SLICE + idx];
    __bf16 hh = (__bf16)s;
    ctxTh[idx] = hh;
    ctxTl[idx] = (__bf16)(s - (float)hh);
}

// ======================================================================
// out via MFMA, NO LDS. grid (N/64, 32). Wave owns 16 n rows. (R5, verified)
// ======================================================================
__global__ __launch_bounds__(256) void out_mfma(
    const __bf16* __restrict__ Qh, const __bf16* __restrict__ Ql,
    const __bf16* __restrict__ projH, const __bf16* __restrict__ projL,
    const __bf16* __restrict__ ctxTh, const __bf16* __restrict__ ctxTl,
    __bf16* __restrict__ attnH, __bf16* __restrict__ attnL)
{
    const int t    = threadIdx.x;
    const int lane = t & 63;
    const int w    = t >> 6;
    const int lm   = lane & 15;
    const int lq   = lane >> 4;
    const int bh   = blockIdx.y;
    const int b    = bh >> 4, h = bh & 15;
    const int nw   = blockIdx.x * 64 + w * 16;
    const size_t rowbase = (size_t)b * N_ * H_ + (size_t)h * DH_;

    bf16x8 qbh[2], qbl[2];
#pragma unroll
    for (int ks = 0; ks < 2; ++ks) {
        size_t qa = rowbase + (size_t)(nw + lm) * H_ + ks * 32 + lq * 8;
        qbh[ks] = *(const bf16x8*)(Qh + qa);
        qbl[ks] = *(const bf16x8*)(Ql + qa);
    }

    const __bf16* cth = ctxTh + (size_t)bh * CE * M_;
    const __bf16* ctl = ctxTl + (size_t)bh * CE * M_;

    f32x4 accO[4];
#pragma unroll
    for (int ef = 0; ef < 4; ++ef) accO[ef] = (f32x4){0.f, 0.f, 0.f, 0.f};
    float den = 0.f;

    for (int mc = 0; mc < 4; ++mc) {
        const int m0 = mc * 64;
        f32x4 dsh[4];
#pragma unroll
        for (int mf = 0; mf < 4; ++mf) {
            dsh[mf] = (f32x4){0.f, 0.f, 0.f, 0.f};
#pragma unroll
            for (int ks = 0; ks < 2; ++ks) {
                size_t pa = (size_t)(m0 + mf * 16 + lm) * 64 + ks * 32 + lq * 8;
                bf16x8 pfh = *(const bf16x8*)(projH + pa);
                bf16x8 pfl = *(const bf16x8*)(projL + pa);
                dsh[mf] = __builtin_amdgcn_mfma_f32_16x16x32_bf16(pfh, qbh[ks], dsh[mf], 0, 0, 0);
                dsh[mf] = __builtin_amdgcn_mfma_f32_16x16x32_bf16(pfl, qbh[ks], dsh[mf], 0, 0, 0);
                dsh[mf] = __builtin_amdgcn_mfma_f32_16x16x32_bf16(pfh, qbl[ks], dsh[mf], 0, 0, 0);
            }
        }
        bf16x4 vh[4], vl[4];
#pragma unroll
        for (int mf = 0; mf < 4; ++mf) {
            bf16x4 kh = *(const bf16x4*)(cth + 64 * M_ + m0 + mf * 16 + lq * 4);
            bf16x4 kl = *(const bf16x4*)(ctl + 64 * M_ + m0 + mf * 16 + lq * 4);
#pragma unroll
            for (int r = 0; r < 4; ++r) {
                float qf = RATIO * (__expf(NORMALIZER * dsh[mf][r]) + KEPS);
                den = fmaf(qf, (float)kh[r] + (float)kl[r], den);
                __bf16 hh = (__bf16)qf;
                vh[mf][r] = hh;
                vl[mf][r] = (__bf16)(qf - (float)hh);
            }
        }
#pragma unroll
        for (int ks2 = 0; ks2 < 2; ++ks2) {
            int s0 = ((2 * lq + 0) & 3) * 16 + lm;
            int s1 = ((2 * lq + 1) & 3) * 16 + lm;
            bf16x4 aH0 = shfl4(vh[2 * ks2 + 0], s0);
            bf16x4 aH1 = shfl4(vh[2 * ks2 + 0], s1);
            bf16x4 bH0 = shfl4(vh[2 * ks2 + 1], s0);
            bf16x4 bH1 = shfl4(vh[2 * ks2 + 1], s1);
            bf16x4 aL0 = shfl4(vl[2 * ks2 + 0], s0);
            bf16x4 aL1 = shfl4(vl[2 * ks2 + 0], s1);
            bf16x4 bL0 = shfl4(vl[2 * ks2 + 1], s0);
            bf16x4 bL1 = shfl4(vl[2 * ks2 + 1], s1);
            bf16x8 afh = (lq & 2) ? cat44(bH0, bH1) : cat44(aH0, aH1);
            bf16x8 afl = (lq & 2) ? cat44(bL0, bL1) : cat44(aL0, aL1);
#pragma unroll
            for (int ef = 0; ef < 4; ++ef) {
                size_t ca = (size_t)(ef * 16 + lm) * M_ + m0 + ks2 * 32 + lq * 8;
                bf16x8 bfh = *(const bf16x8*)(cth + ca);
                bf16x8 bfl = *(const bf16x8*)(ctl + ca);
                accO[ef] = __builtin_amdgcn_mfma_f32_16x16x32_bf16(afh, bfh, accO[ef], 0, 0, 0);
                accO[ef] = __builtin_amdgcn_mfma_f32_16x16x32_bf16(afl, bfh, accO[ef], 0, 0, 0);
                accO[ef] = __builtin_amdgcn_mfma_f32_16x16x32_bf16(afh, bfl, accO[ef], 0, 0, 0);
            }
        }
    }

    den += __shfl_xor(den, 16);
    den += __shfl_xor(den, 32);
    float dinv = 1.f / den;
    float dr[4];
#pragma unroll
    for (int r = 0; r < 4; ++r) dr[r] = __shfl(dinv, lq * 4 + r);

#pragma unroll
    for (int ef = 0; ef < 4; ++ef)
#pragma unroll
        for (int r = 0; r < 4; ++r) {
            float o = accO[ef][r] * dr[r];
            __bf16 hh = (__bf16)o;
            size_t oa = rowbase + (size_t)(nw + lq * 4 + r) * H_ + ef * 16 + lm;
            attnH[oa] = hh;
            attnL[oa] = (__bf16)(o - (float)hh);
        }
}

// ======================================================================
extern "C" void kernel_launch(void* const* d_in, const int* in_sizes, int n_in,
                              void* d_out, int out_size, void* d_ws, size_t ws_size,
                              hipStream_t stream) {
    const float* hs   = (const float*)d_in[0];
    const float* Wq   = (const float*)d_in[1];
    const float* bq   = (const float*)d_in[2];
    const float* Wk   = (const float*)d_in[3];
    const float* bk   = (const float*)d_in[4];
    const float* Wv   = (const float*)d_in[5];
    const float* bv   = (const float*)d_in[6];
    const float* Wo   = (const float*)d_in[7];
    const float* bo   = (const float*)d_in[8];
    const float* proj = (const float*)d_in[9];
    float* out = (float*)d_out;

    const size_t QSZ  = (size_t)B_ * N_ * H_;             // 8388608
    const size_t WSZ  = (size_t)H_ * H_;                  // 1048576
    const size_t CTXT = (size_t)B_ * HEADS_ * CE * M_;    // 532480

    __bf16* Qh  = (__bf16*)d_ws;
    __bf16* Ql  = Qh + QSZ;
    __bf16* Kh  = Ql + QSZ;
    __bf16* Kl  = Kh + QSZ;
    __bf16* Vth = Kl + QSZ;      // V transposed [col][token]
    __bf16* Vtl = Vth + QSZ;
    __bf16* hsH = Vtl + QSZ;     // aliased as attnH after hs consumed
    __bf16* hsL = hsH + QSZ;     // aliased as attnL
    __bf16* WH  = hsL + QSZ;
    __bf16* WL  = WH + 4 * WSZ;
    __bf16* projH = WL + 4 * WSZ;
    __bf16* projL = projH + (size_t)M_ * DH_;
    __bf16* ctxTh = projL + (size_t)M_ * DH_;
    __bf16* ctxTl = ctxTh + CTXT;
    float*  diag  = (float*)(ctxTl + CTXT);
    float*  parts = diag + (size_t)B_ * HEADS_ * N_;
    float*  stab  = parts + 2048;
    float*  ctxp  = stab + 16;

    __bf16 *WqH = WH, *WkH = WH + WSZ, *WvH = WH + 2*WSZ, *WoH = WH + 3*WSZ;
    __bf16 *WqL = WL, *WkL = WL + WSZ, *WvL = WL + 2*WSZ, *WoL = WL + 3*WSZ;

    // 0) splits
    split_bf16<<<QSZ / 4 / 256, 256, 0, stream>>>(hs, hsH, hsL);
    split_w<<<dim3(WSZ / 4 / 256, 4), 256, 0, stream>>>(Wq, Wk, Wv, Wo, WH, WL);
    split_bf16<<<(M_ * DH_) / 4 / 256, 256, 0, stream>>>(proj, projH, projL);

    // 1) Q,K,V = hs @ W^T + b  -> bf16 hi/lo; V written transposed
    gemm_mfma3<true, true><<<dim3(H_ / 128, (B_ * N_) / 128, 3), 256, 0, stream>>>(
        hsH, hsL, WqH, WqL, WkH, WkL, WvH, WvL, bq, bk, bv,
        nullptr, Qh, Ql, Kh, Kl, Vth, Vtl);

    // 2) diag + global stabilizer
    diag_kernel<<<2048, 256, 0, stream>>>(Kh, Kl, diag, parts);
    reduce_stab<<<1, 256, 0, stream>>>(parts, stab, 2048);

    // 3) ctx partials (MFMA, zero LDS)
    ctx_mfma<<<dim3(NSPLIT, 2, B_ * HEADS_), 256, 0, stream>>>(
        Kh, Kl, Vth, Vtl, projH, projL, diag, stab, ctxp);

    // 4) reduce partials -> bf16 ctxT [bh][65][256]
    ctx_reduce<<<(B_ * HEADS_ * CE * M_) / 256, 256, 0, stream>>>(ctxp, ctxTh, ctxTl);

    // 5) out (MFMA, no LDS), writes attn bf16 hi/lo (aliases hs buffers)
    out_mfma<<<dim3(N_ / 64, B_ * HEADS_), 256, 0, stream>>>(
        Qh, Ql, projH, projL, ctxTh, ctxTl, hsH, hsL);

    // 6) final projection fp32 out
    gemm_mfma3<false, false><<<dim3(H_ / 128, (B_ * N_) / 128, 1), 256, 0, stream>>>(
        hsH, hsL, WoH, WoL, WoH, WoL, WoH, WoL, bo, bo, bo,
        out, nullptr, nullptr, nullptr, nullptr, nullptr, nullptr);
}

// Round 7
// 585.638 us; speedup vs baseline: 1.0287x; 1.0287x over previous
//
#include <hip/hip_runtime.h>
#include <math.h>

#define B_      2
#define N_      4096
#define H_      1024
#define HEADS_  16
#define DH_     64
#define M_      256
#define NSPLIT  8
#define EPAD    80

constexpr float NORMALIZER = 0.35355339059327373f; // 64^-0.25
constexpr float RATIO      = 0.0625f;              // 256^-0.5
constexpr float KEPS       = 1e-3f;

typedef __bf16 bf16x8 __attribute__((ext_vector_type(8)));
typedef __bf16 bf16x4 __attribute__((ext_vector_type(4)));
typedef float  f32x4  __attribute__((ext_vector_type(4)));

// ======================================================================
// Split fp32 -> bf16 (hi, lo)
// ======================================================================
__global__ __launch_bounds__(256) void split_bf16(
    const float* __restrict__ src, __bf16* __restrict__ hi, __bf16* __restrict__ lo)
{
    int i = blockIdx.x * 256 + threadIdx.x;
    float4 v = ((const float4*)src)[i];
    float vv[4] = {v.x, v.y, v.z, v.w};
    bf16x4 h, l;
#pragma unroll
    for (int j = 0; j < 4; ++j) {
        __bf16 hh = (__bf16)vv[j];
        h[j] = hh;
        l[j] = (__bf16)(vv[j] - (float)hh);
    }
    ((bf16x4*)hi)[i] = h;
    ((bf16x4*)lo)[i] = l;
}

__global__ __launch_bounds__(256) void split_w(
    const float* __restrict__ W0, const float* __restrict__ W1,
    const float* __restrict__ W2, const float* __restrict__ W3,
    __bf16* __restrict__ hi, __bf16* __restrict__ lo)
{
    const float* src = W0;
    if (blockIdx.y == 1) src = W1;
    else if (blockIdx.y == 2) src = W2;
    else if (blockIdx.y == 3) src = W3;
    int i = blockIdx.x * 256 + threadIdx.x;
    size_t o = (size_t)blockIdx.y * 262144 + i;
    float4 v = ((const float4*)src)[i];
    float vv[4] = {v.x, v.y, v.z, v.w};
    bf16x4 h, l;
#pragma unroll
    for (int j = 0; j < 4; ++j) {
        __bf16 hh = (__bf16)vv[j];
        h[j] = hh;
        l[j] = (__bf16)(vv[j] - (float)hh);
    }
    ((bf16x4*)hi)[o] = h;
    ((bf16x4*)lo)[o] = l;
}

// ======================================================================
// Split-bf16 MFMA GEMM, C = A@W^T + bias -> bf16 hi/lo (QKV path).
// ======================================================================
__global__ __launch_bounds__(256, 2) void gemm_mfma3(
    const __bf16* __restrict__ Ah, const __bf16* __restrict__ Al,
    const __bf16* __restrict__ Bh0, const __bf16* __restrict__ Bl0,
    const __bf16* __restrict__ Bh1, const __bf16* __restrict__ Bl1,
    const __bf16* __restrict__ Bh2, const __bf16* __restrict__ Bl2,
    const float* __restrict__ bi0, const float* __restrict__ bi1, const float* __restrict__ bi2,
    __bf16* __restrict__ Ch0, __bf16* __restrict__ Cl0,
    __bf16* __restrict__ Ch1, __bf16* __restrict__ Cl1,
    __bf16* __restrict__ Ch2, __bf16* __restrict__ Cl2)
{
    const __bf16* Bh = Bh0; const __bf16* Bl = Bl0; const float* bias = bi0;
    __bf16* Ch = Ch0; __bf16* Cl = Cl0;
    if (blockIdx.z == 1) { Bh = Bh1; Bl = Bl1; bias = bi1; Ch = Ch1; Cl = Cl1; }
    else if (blockIdx.z == 2) { Bh = Bh2; Bl = Bl2; bias = bi2; Ch = Ch2; Cl = Cl2; }

    __shared__ alignas(16) __bf16 AhS[128][40];
    __shared__ alignas(16) __bf16 AlS[128][40];
    __shared__ alignas(16) __bf16 BhS[128][40];
    __shared__ alignas(16) __bf16 BlS[128][40];

    const int t    = threadIdx.x;
    const int lane = t & 63;
    const int lm   = lane & 15;
    const int lq   = lane >> 4;
    const int wave = t >> 6;
    const int wm   = (wave >> 1) * 64;
    const int wn   = (wave & 1) * 64;
    const int m0   = blockIdx.y * 128;
    const int n0   = blockIdx.x * 128;
    const int K    = 1024;

    f32x4 acc[4][4];
#pragma unroll
    for (int i = 0; i < 4; ++i)
#pragma unroll
        for (int j = 0; j < 4; ++j) acc[i][j] = (f32x4){0.f, 0.f, 0.f, 0.f};

    for (int k0 = 0; k0 < K; k0 += 32) {
        __syncthreads();
#pragma unroll
        for (int i = 0; i < 2; ++i) {
            int idx = i * 256 + t;
            int row = idx >> 2;
            int c8  = (idx & 3) * 8;
            size_t ga = (size_t)(m0 + row) * K + k0 + c8;
            size_t gb = (size_t)(n0 + row) * K + k0 + c8;
            *(float4*)&AhS[row][c8] = *(const float4*)(Ah + ga);
            *(float4*)&AlS[row][c8] = *(const float4*)(Al + ga);
            *(float4*)&BhS[row][c8] = *(const float4*)(Bh + gb);
            *(float4*)&BlS[row][c8] = *(const float4*)(Bl + gb);
        }
        __syncthreads();

        bf16x8 bh[4], bl[4];
#pragma unroll
        for (int j = 0; j < 4; ++j) {
            bh[j] = *(const bf16x8*)&BhS[wn + j * 16 + lm][lq * 8];
            bl[j] = *(const bf16x8*)&BlS[wn + j * 16 + lm][lq * 8];
        }
#pragma unroll
        for (int i = 0; i < 4; ++i) {
            bf16x8 ah = *(const bf16x8*)&AhS[wm + i * 16 + lm][lq * 8];
            bf16x8 al = *(const bf16x8*)&AlS[wm + i * 16 + lm][lq * 8];
#pragma unroll
            for (int j = 0; j < 4; ++j) {
                acc[i][j] = __builtin_amdgcn_mfma_f32_16x16x32_bf16(ah, bh[j], acc[i][j], 0, 0, 0);
                acc[i][j] = __builtin_amdgcn_mfma_f32_16x16x32_bf16(al, bh[j], acc[i][j], 0, 0, 0);
                acc[i][j] = __builtin_amdgcn_mfma_f32_16x16x32_bf16(ah, bl[j], acc[i][j], 0, 0, 0);
            }
        }
    }

    float bsr[4];
#pragma unroll
    for (int j = 0; j < 4; ++j) bsr[j] = bias[n0 + wn + j * 16 + lm];
#pragma unroll
    for (int i = 0; i < 4; ++i)
#pragma unroll
        for (int r = 0; r < 4; ++r) {
            int rowm = m0 + wm + i * 16 + lq * 4 + r;
#pragma unroll
            for (int j = 0; j < 4; ++j) {
                int col = n0 + wn + j * 16 + lm;
                float o = acc[i][j][r] + bsr[j];
                __bf16 hh = (__bf16)o;
                Ch[(size_t)rowm * 1024 + col] = hh;
                Cl[(size_t)rowm * 1024 + col] = (__bf16)(o - (float)hh);
            }
        }
}

// ======================================================================
// K-split Wo GEMM: z in {0,1} computes k-range [z*512, z*512+512) partial
// (no bias), fp32 out to P[z]. 1024 blocks -> 4 blocks/CU (LDS limit).
// ======================================================================
__global__ __launch_bounds__(256, 2) void gemm_ksplit(
    const __bf16* __restrict__ Ah, const __bf16* __restrict__ Al,
    const __bf16* __restrict__ Bh, const __bf16* __restrict__ Bl,
    float* __restrict__ P0, float* __restrict__ P1)
{
    float* P = blockIdx.z ? P1 : P0;
    const int kbase = blockIdx.z * 512;

    __shared__ alignas(16) __bf16 AhS[128][40];
    __shared__ alignas(16) __bf16 AlS[128][40];
    __shared__ alignas(16) __bf16 BhS[128][40];
    __shared__ alignas(16) __bf16 BlS[128][40];

    const int t    = threadIdx.x;
    const int lane = t & 63;
    const int lm   = lane & 15;
    const int lq   = lane >> 4;
    const int wave = t >> 6;
    const int wm   = (wave >> 1) * 64;
    const int wn   = (wave & 1) * 64;
    const int m0   = blockIdx.y * 128;
    const int n0   = blockIdx.x * 128;
    const int K    = 1024;

    f32x4 acc[4][4];
#pragma unroll
    for (int i = 0; i < 4; ++i)
#pragma unroll
        for (int j = 0; j < 4; ++j) acc[i][j] = (f32x4){0.f, 0.f, 0.f, 0.f};

    for (int kk = 0; kk < 512; kk += 32) {
        const int k0 = kbase + kk;
        __syncthreads();
#pragma unroll
        for (int i = 0; i < 2; ++i) {
            int idx = i * 256 + t;
            int row = idx >> 2;
            int c8  = (idx & 3) * 8;
            size_t ga = (size_t)(m0 + row) * K + k0 + c8;
            size_t gb = (size_t)(n0 + row) * K + k0 + c8;
            *(float4*)&AhS[row][c8] = *(const float4*)(Ah + ga);
            *(float4*)&AlS[row][c8] = *(const float4*)(Al + ga);
            *(float4*)&BhS[row][c8] = *(const float4*)(Bh + gb);
            *(float4*)&BlS[row][c8] = *(const float4*)(Bl + gb);
        }
        __syncthreads();

        bf16x8 bh[4], bl[4];
#pragma unroll
        for (int j = 0; j < 4; ++j) {
            bh[j] = *(const bf16x8*)&BhS[wn + j * 16 + lm][lq * 8];
            bl[j] = *(const bf16x8*)&BlS[wn + j * 16 + lm][lq * 8];
        }
#pragma unroll
        for (int i = 0; i < 4; ++i) {
            bf16x8 ah = *(const bf16x8*)&AhS[wm + i * 16 + lm][lq * 8];
            bf16x8 al = *(const bf16x8*)&AlS[wm + i * 16 + lm][lq * 8];
#pragma unroll
            for (int j = 0; j < 4; ++j) {
                acc[i][j] = __builtin_amdgcn_mfma_f32_16x16x32_bf16(ah, bh[j], acc[i][j], 0, 0, 0);
                acc[i][j] = __builtin_amdgcn_mfma_f32_16x16x32_bf16(al, bh[j], acc[i][j], 0, 0, 0);
                acc[i][j] = __builtin_amdgcn_mfma_f32_16x16x32_bf16(ah, bl[j], acc[i][j], 0, 0, 0);
            }
        }
    }

#pragma unroll
    for (int i = 0; i < 4; ++i)
#pragma unroll
        for (int r = 0; r < 4; ++r) {
            int rowm = m0 + wm + i * 16 + lq * 4 + r;
#pragma unroll
            for (int j = 0; j < 4; ++j) {
                int col = n0 + wn + j * 16 + lm;
                P[(size_t)rowm * 1024 + col] = acc[i][j][r];
            }
        }
}

// out = P0 + P1 + bias (fp32, float4)
__global__ __launch_bounds__(256) void add_bias2(
    const float* __restrict__ P0, const float* __restrict__ P1,
    const float* __restrict__ bias, float* __restrict__ out)
{
    int i = blockIdx.x * 256 + threadIdx.x;         // float4 index
    int col = (i * 4) & 1023;
    float4 a = ((const float4*)P0)[i];
    float4 b = ((const float4*)P1)[i];
    float4 c = *(const float4*)(bias + col);
    float4 o = {a.x + b.x + c.x, a.y + b.y + c.y, a.z + b.z + c.z, a.w + b.w + c.w};
    ((float4*)out)[i] = o;
}

// ======================================================================
// diag_k from bf16 hi/lo K
// ======================================================================
__global__ __launch_bounds__(256) void diag_kernel(
    const __bf16* __restrict__ Kh, const __bf16* __restrict__ Kl,
    float* __restrict__ diag, float* __restrict__ partials)
{
    int gt = blockIdx.x * 256 + threadIdx.x;
    int r  = gt >> 2;
    int q  = gt & 3;
    const bf16x8* ph = (const bf16x8*)(Kh + (size_t)r * 64 + q * 16);
    const bf16x8* pl = (const bf16x8*)(Kl + (size_t)r * 64 + q * 16);
    float s = 0.f;
#pragma unroll
    for (int i = 0; i < 2; ++i) {
        bf16x8 vh = ph[i], vl = pl[i];
#pragma unroll
        for (int j = 0; j < 8; ++j) {
            float x = (float)vh[j] + (float)vl[j];
            s += x * x;
        }
    }
    s += __shfl_xor(s, 1);
    s += __shfl_xor(s, 2);
    float d = -0.5f * s;
    if (q == 0) {
        int h = r & 15, bn = r >> 4;
        int n = bn & 4095, b = bn >> 12;
        diag[(((size_t)b * 16 + h) << 12) + n] = d;
    }
    __shared__ float red[256];
    red[threadIdx.x] = d;
    __syncthreads();
    for (int s2 = 128; s2 > 0; s2 >>= 1) {
        if (threadIdx.x < s2) red[threadIdx.x] = fmaxf(red[threadIdx.x], red[threadIdx.x + s2]);
        __syncthreads();
    }
    if (threadIdx.x == 0) partials[blockIdx.x] = red[0];
}

__global__ __launch_bounds__(256) void reduce_stab(
    const float* __restrict__ partials, float* __restrict__ stab, int n)
{
    float m = -3.0e38f;
    for (int i = threadIdx.x; i < n; i += 256) m = fmaxf(m, partials[i]);
    __shared__ float red[256];
    red[threadIdx.x] = m;
    __syncthreads();
    for (int s2 = 128; s2 > 0; s2 >>= 1) {
        if (threadIdx.x < s2) red[threadIdx.x] = fmaxf(red[threadIdx.x], red[threadIdx.x + s2]);
        __syncthreads();
    }
    if (threadIdx.x == 0) stab[0] = red[0];
}

// ======================================================================
// ctx via MFMA (R3-verified structure). grid (NSPLIT, 2, 32).
// kf stores vectorized to bf16x4 (ds_write_b64) — only change vs R3.
// ======================================================================
__global__ __launch_bounds__(256) void ctx_mfma(
    const __bf16* __restrict__ Kh, const __bf16* __restrict__ Kl,
    const __bf16* __restrict__ Vh, const __bf16* __restrict__ Vl,
    const __bf16* __restrict__ projH, const __bf16* __restrict__ projL,
    const float* __restrict__ diag, const float* __restrict__ stabp,
    float* __restrict__ ctxp)
{
    __shared__ alignas(16) char ldsbuf[59904];
    __shared__ float dg[64];
    __bf16* kfTh = (__bf16*)ldsbuf;              // [128][72]
    __bf16* kfTl = kfTh + 9216;                  // [128][72]
    __bf16* vTh  = kfTl + 9216;                  // [80][72]
    __bf16* vTl  = vTh + 5760;                   // [80][72]
    float*  ctxe = (float*)ldsbuf;               // [128][81] (epilogue alias)

    const int t    = threadIdx.x;
    const int lane = t & 63;
    const int w    = t >> 6;
    const int lm   = lane & 15;
    const int lq   = lane >> 4;
    const int bh   = blockIdx.z;
    const int b    = bh >> 4, h = bh & 15;
    const int mh   = blockIdx.y;
    const int slice = blockIdx.x;
    const int mwave = mh * 128 + w * 32;          // global m base for wave
    const float stab = stabp[0];
    const size_t rowbase = (size_t)b * N_ * H_ + (size_t)h * DH_;
    const float* diag_bh = diag + (size_t)bh * N_;

    // vT constant rows: e=64 -> ones (hi), e>64 -> zero
    for (int idx = t; idx < 16 * 72; idx += 256) {
        int e = 64 + idx / 72, n = idx % 72;
        vTh[e * 72 + n] = (e == 64 && n < 64) ? (__bf16)1.0f : (__bf16)0.0f;
        vTl[e * 72 + n] = (__bf16)0.0f;
    }

    // proj B-frags, register-cached for whole kernel: [mf][ks]
    bf16x8 ph[2][2], pl[2][2];
#pragma unroll
    for (int mf = 0; mf < 2; ++mf)
#pragma unroll
        for (int ks = 0; ks < 2; ++ks) {
            size_t pa = (size_t)(mwave + mf * 16 + lm) * 64 + ks * 32 + lq * 8;
            ph[mf][ks] = *(const bf16x8*)(projH + pa);
            pl[mf][ks] = *(const bf16x8*)(projL + pa);
        }

    f32x4 acc[2][5];
#pragma unroll
    for (int mf = 0; mf < 2; ++mf)
#pragma unroll
        for (int ef = 0; ef < 5; ++ef) acc[mf][ef] = (f32x4){0.f, 0.f, 0.f, 0.f};

    for (int tile = 0; tile < 8; ++tile) {
        const int n0 = slice * (N_ / NSPLIT) + tile * 64;
        __syncthreads();   // barrier A: prior GEMM reads of vT done

        // stage vT rows 0..63 (transpose V[n][d] -> vT[d][n])
        {
            int nl = t >> 2, dc = (t & 3) * 16;
            size_t va = rowbase + (size_t)(n0 + nl) * H_ + dc;
            bf16x8 v0 = *(const bf16x8*)(Vh + va);
            bf16x8 v1 = *(const bf16x8*)(Vh + va + 8);
            bf16x8 u0 = *(const bf16x8*)(Vl + va);
            bf16x8 u1 = *(const bf16x8*)(Vl + va + 8);
#pragma unroll
            for (int j = 0; j < 8; ++j) {
                vTh[(dc + j) * 72 + nl]     = v0[j];
                vTh[(dc + 8 + j) * 72 + nl] = v1[j];
                vTl[(dc + j) * 72 + nl]     = u0[j];
                vTl[(dc + 8 + j) * 72 + nl] = u1[j];
            }
        }
        if (t < 64) dg[t] = diag_bh[n0 + t] - stab;

        // dash MFMA (global operands, no LDS dependency)
        f32x4 dsh[4][2];
#pragma unroll
        for (int nf = 0; nf < 4; ++nf) {
#pragma unroll
            for (int mf = 0; mf < 2; ++mf) dsh[nf][mf] = (f32x4){0.f, 0.f, 0.f, 0.f};
            bf16x8 ah[2], al[2];
#pragma unroll
            for (int ks = 0; ks < 2; ++ks) {
                size_t ka = rowbase + (size_t)(n0 + nf * 16 + lm) * H_ + ks * 32 + lq * 8;
                ah[ks] = *(const bf16x8*)(Kh + ka);
                al[ks] = *(const bf16x8*)(Kl + ka);
            }
#pragma unroll
            for (int mf = 0; mf < 2; ++mf)
#pragma unroll
                for (int ks = 0; ks < 2; ++ks) {
                    dsh[nf][mf] = __builtin_amdgcn_mfma_f32_16x16x32_bf16(ah[ks], ph[mf][ks], dsh[nf][mf], 0, 0, 0);
                    dsh[nf][mf] = __builtin_amdgcn_mfma_f32_16x16x32_bf16(al[ks], ph[mf][ks], dsh[nf][mf], 0, 0, 0);
                    dsh[nf][mf] = __builtin_amdgcn_mfma_f32_16x16x32_bf16(ah[ks], pl[mf][ks], dsh[nf][mf], 0, 0, 0);
                }
        }

        __syncthreads();   // barrier B: vT + dg staged

        // exp -> kf bf16 hi/lo -> kfT (wave-private rows), vectorized b64 stores
#pragma unroll
        for (int nf = 0; nf < 4; ++nf) {
            float4 dgv = *(const float4*)&dg[nf * 16 + lq * 4];
            float dga[4] = {dgv.x, dgv.y, dgv.z, dgv.w};
#pragma unroll
            for (int mf = 0; mf < 2; ++mf) {
                int mrow = w * 32 + mf * 16 + lm;   // block-local m row
                bf16x4 hh4, ll4;
#pragma unroll
                for (int r = 0; r < 4; ++r) {
                    float kf = RATIO * (__expf(dga[r] + NORMALIZER * dsh[nf][mf][r]) + KEPS);
                    __bf16 hh = (__bf16)kf;
                    hh4[r] = hh;
                    ll4[r] = (__bf16)(kf - (float)hh);
                }
                int ncol = nf * 16 + lq * 4;
                *(bf16x4*)&kfTh[mrow * 72 + ncol] = hh4;
                *(bf16x4*)&kfTl[mrow * 72 + ncol] = ll4;
            }
        }

        // ctx accumulate: acc[mf][ef] += kfT[m][n] @ vT[e][n]
#pragma unroll
        for (int ks = 0; ks < 2; ++ks) {
#pragma unroll
            for (int mf = 0; mf < 2; ++mf) {
                bf16x8 af = *(const bf16x8*)&kfTh[(w * 32 + mf * 16 + lm) * 72 + ks * 32 + lq * 8];
                bf16x8 afl = *(const bf16x8*)&kfTl[(w * 32 + mf * 16 + lm) * 72 + ks * 32 + lq * 8];
#pragma unroll
                for (int ef = 0; ef < 5; ++ef) {
                    bf16x8 bfh = *(const bf16x8*)&vTh[(ef * 16 + lm) * 72 + ks * 32 + lq * 8];
                    bf16x8 bfl = *(const bf16x8*)&vTl[(ef * 16 + lm) * 72 + ks * 32 + lq * 8];
                    acc[mf][ef] = __builtin_amdgcn_mfma_f32_16x16x32_bf16(af,  bfh, acc[mf][ef], 0, 0, 0);
                    acc[mf][ef] = __builtin_amdgcn_mfma_f32_16x16x32_bf16(afl, bfh, acc[mf][ef], 0, 0, 0);
                    acc[mf][ef] = __builtin_amdgcn_mfma_f32_16x16x32_bf16(af,  bfl, acc[mf][ef], 0, 0, 0);
                }
            }
        }
    }

    // epilogue: acc -> ctxe[m][e] (fp32, pad 81) -> coalesced global [s][bh][e][m]
    __syncthreads();
#pragma unroll
    for (int mf = 0; mf < 2; ++mf)
#pragma unroll
        for (int ef = 0; ef < 5; ++ef)
#pragma unroll
            for (int r = 0; r < 4; ++r) {
                int ml = w * 32 + mf * 16 + lq * 4 + r;
                int e  = ef * 16 + lm;
                ctxe[ml * 81 + e] = acc[mf][ef][r];
            }
    __syncthreads();
    const size_t SLICE = (size_t)(B_ * HEADS_) * EPAD * M_;
    const size_t obase = (size_t)slice * SLICE + (size_t)bh * EPAD * M_;
    for (int i = t; i < EPAD * 128; i += 256) {
        int e = i >> 7, ml = i & 127;
        ctxp[obase + (size_t)e * M_ + mh * 128 + ml] = ctxe[ml * 81 + e];
    }
}

// ======================================================================
// Reduce ctx partials over slices -> bf16 hi/lo ctxT[bh][e][m]
// ======================================================================
__global__ __launch_bounds__(256) void ctx_reduce(
    const float* __restrict__ ctxp, __bf16* __restrict__ ctxTh, __bf16* __restrict__ ctxTl)
{
    int idx = blockIdx.x * 256 + threadIdx.x;     // [0, 32*80*256)
    const size_t SLICE = (size_t)(B_ * HEADS_) * EPAD * M_;
    float s = 0.f;
#pragma unroll
    for (int k = 0; k < NSPLIT; ++k) s += ctxp[(size_t)k * SLICE + idx];
    __bf16 hh = (__bf16)s;
    ctxTh[idx] = hh;
    ctxTl[idx] = (__bf16)(s - (float)hh);
}

// ======================================================================
// out via MFMA (R3-verified). grid (N/64, 32). 4 waves, wave owns 16 n rows.
// qf LDS roundtrip, no barriers (wave-private LDS rows).
// ======================================================================
__global__ __launch_bounds__(256) void out_mfma(
    const __bf16* __restrict__ Qh, const __bf16* __restrict__ Ql,
    const __bf16* __restrict__ projH, const __bf16* __restrict__ projL,
    const __bf16* __restrict__ ctxTh, const __bf16* __restrict__ ctxTl,
    __bf16* __restrict__ attnH, __bf16* __restrict__ attnL)
{
    __shared__ alignas(16) __bf16 qfh[4][16][72];
    __shared__ alignas(16) __bf16 qfl[4][16][72];

    const int t    = threadIdx.x;
    const int lane = t & 63;
    const int w    = t >> 6;
    const int lm   = lane & 15;
    const int lq   = lane >> 4;
    const int bh   = blockIdx.y;
    const int b    = bh >> 4, h = bh & 15;
    const int nw   = blockIdx.x * 64 + w * 16;    // wave's n base
    const size_t rowbase = (size_t)b * N_ * H_ + (size_t)h * DH_;

    // A dash frags (q rows), loaded once
    bf16x8 qh_[2], ql_[2];
#pragma unroll
    for (int ks = 0; ks < 2; ++ks) {
        size_t qa = rowbase + (size_t)(nw + lm) * H_ + ks * 32 + lq * 8;
        qh_[ks] = *(const bf16x8*)(Qh + qa);
        ql_[ks] = *(const bf16x8*)(Ql + qa);
    }

    const __bf16* cth = ctxTh + (size_t)bh * EPAD * M_;
    const __bf16* ctl = ctxTl + (size_t)bh * EPAD * M_;

    f32x4 accO[5];
#pragma unroll
    for (int ef = 0; ef < 5; ++ef) accO[ef] = (f32x4){0.f, 0.f, 0.f, 0.f};

    for (int mc = 0; mc < 4; ++mc) {
        const int m0 = mc * 64;
        // dash
        f32x4 dsh[4];
#pragma unroll
        for (int mf = 0; mf < 4; ++mf) {
            dsh[mf] = (f32x4){0.f, 0.f, 0.f, 0.f};
#pragma unroll
            for (int ks = 0; ks < 2; ++ks) {
                size_t pa = (size_t)(m0 + mf * 16 + lm) * 64 + ks * 32 + lq * 8;
                bf16x8 ph = *(const bf16x8*)(projH + pa);
                bf16x8 pl = *(const bf16x8*)(projL + pa);
                dsh[mf] = __builtin_amdgcn_mfma_f32_16x16x32_bf16(qh_[ks], ph, dsh[mf], 0, 0, 0);
                dsh[mf] = __builtin_amdgcn_mfma_f32_16x16x32_bf16(ql_[ks], ph, dsh[mf], 0, 0, 0);
                dsh[mf] = __builtin_amdgcn_mfma_f32_16x16x32_bf16(qh_[ks], pl, dsh[mf], 0, 0, 0);
            }
        }
        // exp -> qf bf16 hi/lo -> wave-private LDS [n16][m64]
#pragma unroll
        for (int mf = 0; mf < 4; ++mf)
#pragma unroll
            for (int r = 0; r < 4; ++r) {
                float qf = RATIO * (__expf(NORMALIZER * dsh[mf][r]) + KEPS);
                __bf16 hh = (__bf16)qf;
                int nloc = lq * 4 + r;
                qfh[w][nloc][mf * 16 + lm] = hh;
                qfl[w][nloc][mf * 16 + lm] = (__bf16)(qf - (float)hh);
            }
        // out GEMM: acc += qf[n][m] @ ctxT[e][m]
#pragma unroll
        for (int ks = 0; ks < 2; ++ks) {
            bf16x8 af  = *(const bf16x8*)&qfh[w][lm][ks * 32 + lq * 8];
            bf16x8 afl = *(const bf16x8*)&qfl[w][lm][ks * 32 + lq * 8];
#pragma unroll
            for (int ef = 0; ef < 5; ++ef) {
                size_t ca = (size_t)(ef * 16 + lm) * M_ + m0 + ks * 32 + lq * 8;
                bf16x8 bfh = *(const bf16x8*)(cth + ca);
                bf16x8 bfl = *(const bf16x8*)(ctl + ca);
                accO[ef] = __builtin_amdgcn_mfma_f32_16x16x32_bf16(af,  bfh, accO[ef], 0, 0, 0);
                accO[ef] = __builtin_amdgcn_mfma_f32_16x16x32_bf16(afl, bfh, accO[ef], 0, 0, 0);
                accO[ef] = __builtin_amdgcn_mfma_f32_16x16x32_bf16(af,  bfl, accO[ef], 0, 0, 0);
            }
        }
    }

    // denominator: ctx column 64 -> accO[4] col (64 + lm); lm==0 holds den[row]
    float dinv[4];
#pragma unroll
    for (int r = 0; r < 4; ++r) {
        float den = __shfl(accO[4][r], lane & 48);
        dinv[r] = 1.f / den;
    }
#pragma unroll
    for (int ef = 0; ef < 4; ++ef)
#pragma unroll
        for (int r = 0; r < 4; ++r) {
            float o = accO[ef][r] * dinv[r];
            __bf16 hh = (__bf16)o;
            size_t oa = rowbase + (size_t)(nw + lq * 4 + r) * H_ + ef * 16 + lm;
            attnH[oa] = hh;
            attnL[oa] = (__bf16)(o - (float)hh);
        }
}

// ======================================================================
extern "C" void kernel_launch(void* const* d_in, const int* in_sizes, int n_in,
                              void* d_out, int out_size, void* d_ws, size_t ws_size,
                              hipStream_t stream) {
    const float* hs   = (const float*)d_in[0];
    const float* Wq   = (const float*)d_in[1];
    const float* bq   = (const float*)d_in[2];
    const float* Wk   = (const float*)d_in[3];
    const float* bk   = (const float*)d_in[4];
    const float* Wv   = (const float*)d_in[5];
    const float* bv   = (const float*)d_in[6];
    const float* Wo   = (const float*)d_in[7];
    const float* bo   = (const float*)d_in[8];
    const float* proj = (const float*)d_in[9];
    float* out = (float*)d_out;

    const size_t QSZ  = (size_t)B_ * N_ * H_;             // 8388608
    const size_t WSZ  = (size_t)H_ * H_;                  // 1048576
    const size_t CTXT = (size_t)B_ * HEADS_ * EPAD * M_;  // 655360

    __bf16* Qh  = (__bf16*)d_ws;
    __bf16* Ql  = Qh + QSZ;
    __bf16* Kh  = Ql + QSZ;
    __bf16* Kl  = Kh + QSZ;
    __bf16* Vh  = Kl + QSZ;
    __bf16* Vl  = Vh + QSZ;
    __bf16* hsH = Vl + QSZ;      // aliased as attnH after hs consumed
    __bf16* hsL = hsH + QSZ;     // aliased as attnL
    __bf16* WH  = hsL + QSZ;
    __bf16* WL  = WH + 4 * WSZ;
    __bf16* projH = WL + 4 * WSZ;
    __bf16* projL = projH + (size_t)M_ * DH_;
    __bf16* ctxTh = projL + (size_t)M_ * DH_;
    __bf16* ctxTl = ctxTh + CTXT;
    float*  diag  = (float*)(ctxTl + CTXT);
    float*  parts = diag + (size_t)B_ * HEADS_ * N_;
    float*  stab  = parts + 2048;
    float*  ctxp  = stab + 16;

    // Wo K-split partials alias the (dead by then) K and V hi/lo buffers.
    float* P0 = (float*)Kh;      // 8388608 floats = Kh+Kl region
    float* P1 = (float*)Vh;      // 8388608 floats = Vh+Vl region

    __bf16 *WqH = WH, *WkH = WH + WSZ, *WvH = WH + 2*WSZ, *WoH = WH + 3*WSZ;
    __bf16 *WqL = WL, *WkL = WL + WSZ, *WvL = WL + 2*WSZ, *WoL = WL + 3*WSZ;

    // 0) splits
    split_bf16<<<QSZ / 4 / 256, 256, 0, stream>>>(hs, hsH, hsL);
    split_w<<<dim3(WSZ / 4 / 256, 4), 256, 0, stream>>>(Wq, Wk, Wv, Wo, WH, WL);
    split_bf16<<<(M_ * DH_) / 4 / 256, 256, 0, stream>>>(proj, projH, projL);

    // 1) Q,K,V = hs @ W^T + b  -> bf16 hi/lo
    gemm_mfma3<<<dim3(H_ / 128, (B_ * N_) / 128, 3), 256, 0, stream>>>(
        hsH, hsL, WqH, WqL, WkH, WkL, WvH, WvL, bq, bk, bv,
        Qh, Ql, Kh, Kl, Vh, Vl);

    // 2) diag + global stabilizer
    diag_kernel<<<2048, 256, 0, stream>>>(Kh, Kl, diag, parts);
    reduce_stab<<<1, 256, 0, stream>>>(parts, stab, 2048);

    // 3) ctx partials (MFMA)
    ctx_mfma<<<dim3(NSPLIT, 2, B_ * HEADS_), 256, 0, stream>>>(
        Kh, Kl, Vh, Vl, projH, projL, diag, stab, ctxp);

    // 4) reduce partials -> bf16 ctxT
    ctx_reduce<<<(B_ * HEADS_ * EPAD * M_) / 256, 256, 0, stream>>>(ctxp, ctxTh, ctxTl);

    // 5) out (MFMA), writes attn bf16 hi/lo (aliases hs buffers)
    out_mfma<<<dim3(N_ / 64, B_ * HEADS_), 256, 0, stream>>>(
        Qh, Ql, projH, projL, ctxTh, ctxTl, hsH, hsL);

    // 6) final projection, K-split x2 (1024 blocks = 4/CU) + bias-add
    gemm_ksplit<<<dim3(H_ / 128, (B_ * N_) / 128, 2), 256, 0, stream>>>(
        hsH, hsL, WoH, WoL, P0, P1);
    add_bias2<<<(B_ * N_ * H_) / 4 / 256, 256, 0, stream>>>(P0, P1, bo, out);
}

// Round 8
// 564.362 us; speedup vs baseline: 1.0675x; 1.0377x over previous
//
#include <hip/hip_runtime.h>
#include <math.h>

#define B_      2
#define N_      4096
#define H_      1024
#define HEADS_  16
#define DH_     64
#define M_      256
#define NSPLIT  8
#define EPAD    80

constexpr float NORMALIZER = 0.35355339059327373f; // 64^-0.25
constexpr float RATIO      = 0.0625f;              // 256^-0.5
constexpr float KEPS       = 1e-3f;

typedef __bf16 bf16x8 __attribute__((ext_vector_type(8)));
typedef __bf16 bf16x4 __attribute__((ext_vector_type(4)));
typedef float  f32x4  __attribute__((ext_vector_type(4)));

// ======================================================================
// Split fp32 -> bf16 (hi, lo)
// ======================================================================
__global__ __launch_bounds__(256) void split_bf16(
    const float* __restrict__ src, __bf16* __restrict__ hi, __bf16* __restrict__ lo)
{
    int i = blockIdx.x * 256 + threadIdx.x;
    float4 v = ((const float4*)src)[i];
    float vv[4] = {v.x, v.y, v.z, v.w};
    bf16x4 h, l;
#pragma unroll
    for (int j = 0; j < 4; ++j) {
        __bf16 hh = (__bf16)vv[j];
        h[j] = hh;
        l[j] = (__bf16)(vv[j] - (float)hh);
    }
    ((bf16x4*)hi)[i] = h;
    ((bf16x4*)lo)[i] = l;
}

__global__ __launch_bounds__(256) void split_w(
    const float* __restrict__ W0, const float* __restrict__ W1,
    const float* __restrict__ W2, const float* __restrict__ W3,
    __bf16* __restrict__ hi, __bf16* __restrict__ lo)
{
    const float* src = W0;
    if (blockIdx.y == 1) src = W1;
    else if (blockIdx.y == 2) src = W2;
    else if (blockIdx.y == 3) src = W3;
    int i = blockIdx.x * 256 + threadIdx.x;
    size_t o = (size_t)blockIdx.y * 262144 + i;
    float4 v = ((const float4*)src)[i];
    float vv[4] = {v.x, v.y, v.z, v.w};
    bf16x4 h, l;
#pragma unroll
    for (int j = 0; j < 4; ++j) {
        __bf16 hh = (__bf16)vv[j];
        h[j] = hh;
        l[j] = (__bf16)(vv[j] - (float)hh);
    }
    ((bf16x4*)hi)[o] = h;
    ((bf16x4*)lo)[o] = l;
}

// ======================================================================
// Split-bf16 MFMA GEMM, C = A@W^T + bias. Single B matrix per dispatch
// (QKV split into 3 launches so rocprof top-5 can resolve other kernels).
// ======================================================================
template<bool BF16OUT>
__global__ __launch_bounds__(256, 2) void gemm_mfma3(
    const __bf16* __restrict__ Ah, const __bf16* __restrict__ Al,
    const __bf16* __restrict__ Bh, const __bf16* __restrict__ Bl,
    const float* __restrict__ bias,
    float* __restrict__ C0,
    __bf16* __restrict__ Ch, __bf16* __restrict__ Cl)
{
    __shared__ alignas(16) __bf16 AhS[128][40];
    __shared__ alignas(16) __bf16 AlS[128][40];
    __shared__ alignas(16) __bf16 BhS[128][40];
    __shared__ alignas(16) __bf16 BlS[128][40];

    const int t    = threadIdx.x;
    const int lane = t & 63;
    const int lm   = lane & 15;
    const int lq   = lane >> 4;
    const int wave = t >> 6;
    const int wm   = (wave >> 1) * 64;
    const int wn   = (wave & 1) * 64;
    const int m0   = blockIdx.y * 128;
    const int n0   = blockIdx.x * 128;
    const int K    = 1024;

    f32x4 acc[4][4];
#pragma unroll
    for (int i = 0; i < 4; ++i)
#pragma unroll
        for (int j = 0; j < 4; ++j) acc[i][j] = (f32x4){0.f, 0.f, 0.f, 0.f};

    for (int k0 = 0; k0 < K; k0 += 32) {
        __syncthreads();
#pragma unroll
        for (int i = 0; i < 2; ++i) {
            int idx = i * 256 + t;
            int row = idx >> 2;
            int c8  = (idx & 3) * 8;
            size_t ga = (size_t)(m0 + row) * K + k0 + c8;
            size_t gb = (size_t)(n0 + row) * K + k0 + c8;
            *(float4*)&AhS[row][c8] = *(const float4*)(Ah + ga);
            *(float4*)&AlS[row][c8] = *(const float4*)(Al + ga);
            *(float4*)&BhS[row][c8] = *(const float4*)(Bh + gb);
            *(float4*)&BlS[row][c8] = *(const float4*)(Bl + gb);
        }
        __syncthreads();

        bf16x8 bh[4], bl[4];
#pragma unroll
        for (int j = 0; j < 4; ++j) {
            bh[j] = *(const bf16x8*)&BhS[wn + j * 16 + lm][lq * 8];
            bl[j] = *(const bf16x8*)&BlS[wn + j * 16 + lm][lq * 8];
        }
#pragma unroll
        for (int i = 0; i < 4; ++i) {
            bf16x8 ah = *(const bf16x8*)&AhS[wm + i * 16 + lm][lq * 8];
            bf16x8 al = *(const bf16x8*)&AlS[wm + i * 16 + lm][lq * 8];
#pragma unroll
            for (int j = 0; j < 4; ++j) {
                acc[i][j] = __builtin_amdgcn_mfma_f32_16x16x32_bf16(ah, bh[j], acc[i][j], 0, 0, 0);
                acc[i][j] = __builtin_amdgcn_mfma_f32_16x16x32_bf16(al, bh[j], acc[i][j], 0, 0, 0);
                acc[i][j] = __builtin_amdgcn_mfma_f32_16x16x32_bf16(ah, bl[j], acc[i][j], 0, 0, 0);
            }
        }
    }

    float bsr[4];
#pragma unroll
    for (int j = 0; j < 4; ++j) bsr[j] = bias[n0 + wn + j * 16 + lm];
#pragma unroll
    for (int i = 0; i < 4; ++i)
#pragma unroll
        for (int r = 0; r < 4; ++r) {
            int rowm = m0 + wm + i * 16 + lq * 4 + r;
#pragma unroll
            for (int j = 0; j < 4; ++j) {
                int col = n0 + wn + j * 16 + lm;
                float o = acc[i][j][r] + bsr[j];
                if (BF16OUT) {
                    __bf16 hh = (__bf16)o;
                    Ch[(size_t)rowm * 1024 + col] = hh;
                    Cl[(size_t)rowm * 1024 + col] = (__bf16)(o - (float)hh);
                } else {
                    C0[(size_t)rowm * 1024 + col] = o;
                }
            }
        }
}

// ======================================================================
// diag_k from bf16 hi/lo K
// ======================================================================
__global__ __launch_bounds__(256) void diag_kernel(
    const __bf16* __restrict__ Kh, const __bf16* __restrict__ Kl,
    float* __restrict__ diag, float* __restrict__ partials)
{
    int gt = blockIdx.x * 256 + threadIdx.x;
    int r  = gt >> 2;
    int q  = gt & 3;
    const bf16x8* ph = (const bf16x8*)(Kh + (size_t)r * 64 + q * 16);
    const bf16x8* pl = (const bf16x8*)(Kl + (size_t)r * 64 + q * 16);
    float s = 0.f;
#pragma unroll
    for (int i = 0; i < 2; ++i) {
        bf16x8 vh = ph[i], vl = pl[i];
#pragma unroll
        for (int j = 0; j < 8; ++j) {
            float x = (float)vh[j] + (float)vl[j];
            s += x * x;
        }
    }
    s += __shfl_xor(s, 1);
    s += __shfl_xor(s, 2);
    float d = -0.5f * s;
    if (q == 0) {
        int h = r & 15, bn = r >> 4;
        int n = bn & 4095, b = bn >> 12;
        diag[(((size_t)b * 16 + h) << 12) + n] = d;
    }
    __shared__ float red[256];
    red[threadIdx.x] = d;
    __syncthreads();
    for (int s2 = 128; s2 > 0; s2 >>= 1) {
        if (threadIdx.x < s2) red[threadIdx.x] = fmaxf(red[threadIdx.x], red[threadIdx.x + s2]);
        __syncthreads();
    }
    if (threadIdx.x == 0) partials[blockIdx.x] = red[0];
}

__global__ __launch_bounds__(256) void reduce_stab(
    const float* __restrict__ partials, float* __restrict__ stab, int n)
{
    float m = -3.0e38f;
    for (int i = threadIdx.x; i < n; i += 256) m = fmaxf(m, partials[i]);
    __shared__ float red[256];
    red[threadIdx.x] = m;
    __syncthreads();
    for (int s2 = 128; s2 > 0; s2 >>= 1) {
        if (threadIdx.x < s2) red[threadIdx.x] = fmaxf(red[threadIdx.x], red[threadIdx.x + s2]);
        __syncthreads();
    }
    if (threadIdx.x == 0) stab[0] = red[0];
}

// ======================================================================
// ctx via MFMA (R3-verified structure + vectorized kf stores).
// grid (NSPLIT, 2, 32).
// ======================================================================
__global__ __launch_bounds__(256) void ctx_mfma(
    const __bf16* __restrict__ Kh, const __bf16* __restrict__ Kl,
    const __bf16* __restrict__ Vh, const __bf16* __restrict__ Vl,
    const __bf16* __restrict__ projH, const __bf16* __restrict__ projL,
    const float* __restrict__ diag, const float* __restrict__ stabp,
    float* __restrict__ ctxp)
{
    __shared__ alignas(16) char ldsbuf[59904];
    __shared__ float dg[64];
    __bf16* kfTh = (__bf16*)ldsbuf;              // [128][72]
    __bf16* kfTl = kfTh + 9216;                  // [128][72]
    __bf16* vTh  = kfTl + 9216;                  // [80][72]
    __bf16* vTl  = vTh + 5760;                   // [80][72]
    float*  ctxe = (float*)ldsbuf;               // [128][81] (epilogue alias)

    const int t    = threadIdx.x;
    const int lane = t & 63;
    const int w    = t >> 6;
    const int lm   = lane & 15;
    const int lq   = lane >> 4;
    const int bh   = blockIdx.z;
    const int b    = bh >> 4, h = bh & 15;
    const int mh   = blockIdx.y;
    const int slice = blockIdx.x;
    const int mwave = mh * 128 + w * 32;
    const float stab = stabp[0];
    const size_t rowbase = (size_t)b * N_ * H_ + (size_t)h * DH_;
    const float* diag_bh = diag + (size_t)bh * N_;

    for (int idx = t; idx < 16 * 72; idx += 256) {
        int e = 64 + idx / 72, n = idx % 72;
        vTh[e * 72 + n] = (e == 64 && n < 64) ? (__bf16)1.0f : (__bf16)0.0f;
        vTl[e * 72 + n] = (__bf16)0.0f;
    }

    bf16x8 ph[2][2], pl[2][2];
#pragma unroll
    for (int mf = 0; mf < 2; ++mf)
#pragma unroll
        for (int ks = 0; ks < 2; ++ks) {
            size_t pa = (size_t)(mwave + mf * 16 + lm) * 64 + ks * 32 + lq * 8;
            ph[mf][ks] = *(const bf16x8*)(projH + pa);
            pl[mf][ks] = *(const bf16x8*)(projL + pa);
        }

    f32x4 acc[2][5];
#pragma unroll
    for (int mf = 0; mf < 2; ++mf)
#pragma unroll
        for (int ef = 0; ef < 5; ++ef) acc[mf][ef] = (f32x4){0.f, 0.f, 0.f, 0.f};

    for (int tile = 0; tile < 8; ++tile) {
        const int n0 = slice * (N_ / NSPLIT) + tile * 64;
        __syncthreads();   // barrier A

        {
            int nl = t >> 2, dc = (t & 3) * 16;
            size_t va = rowbase + (size_t)(n0 + nl) * H_ + dc;
            bf16x8 v0 = *(const bf16x8*)(Vh + va);
            bf16x8 v1 = *(const bf16x8*)(Vh + va + 8);
            bf16x8 u0 = *(const bf16x8*)(Vl + va);
            bf16x8 u1 = *(const bf16x8*)(Vl + va + 8);
#pragma unroll
            for (int j = 0; j < 8; ++j) {
                vTh[(dc + j) * 72 + nl]     = v0[j];
                vTh[(dc + 8 + j) * 72 + nl] = v1[j];
                vTl[(dc + j) * 72 + nl]     = u0[j];
                vTl[(dc + 8 + j) * 72 + nl] = u1[j];
            }
        }
        if (t < 64) dg[t] = diag_bh[n0 + t] - stab;

        f32x4 dsh[4][2];
#pragma unroll
        for (int nf = 0; nf < 4; ++nf) {
#pragma unroll
            for (int mf = 0; mf < 2; ++mf) dsh[nf][mf] = (f32x4){0.f, 0.f, 0.f, 0.f};
            bf16x8 ah[2], al[2];
#pragma unroll
            for (int ks = 0; ks < 2; ++ks) {
                size_t ka = rowbase + (size_t)(n0 + nf * 16 + lm) * H_ + ks * 32 + lq * 8;
                ah[ks] = *(const bf16x8*)(Kh + ka);
                al[ks] = *(const bf16x8*)(Kl + ka);
            }
#pragma unroll
            for (int mf = 0; mf < 2; ++mf)
#pragma unroll
                for (int ks = 0; ks < 2; ++ks) {
                    dsh[nf][mf] = __builtin_amdgcn_mfma_f32_16x16x32_bf16(ah[ks], ph[mf][ks], dsh[nf][mf], 0, 0, 0);
                    dsh[nf][mf] = __builtin_amdgcn_mfma_f32_16x16x32_bf16(al[ks], ph[mf][ks], dsh[nf][mf], 0, 0, 0);
                    dsh[nf][mf] = __builtin_amdgcn_mfma_f32_16x16x32_bf16(ah[ks], pl[mf][ks], dsh[nf][mf], 0, 0, 0);
                }
        }

        __syncthreads();   // barrier B

#pragma unroll
        for (int nf = 0; nf < 4; ++nf) {
            float4 dgv = *(const float4*)&dg[nf * 16 + lq * 4];
            float dga[4] = {dgv.x, dgv.y, dgv.z, dgv.w};
#pragma unroll
            for (int mf = 0; mf < 2; ++mf) {
                int mrow = w * 32 + mf * 16 + lm;
                bf16x4 hh4, ll4;
#pragma unroll
                for (int r = 0; r < 4; ++r) {
                    float kf = RATIO * (__expf(dga[r] + NORMALIZER * dsh[nf][mf][r]) + KEPS);
                    __bf16 hh = (__bf16)kf;
                    hh4[r] = hh;
                    ll4[r] = (__bf16)(kf - (float)hh);
                }
                int ncol = nf * 16 + lq * 4;
                *(bf16x4*)&kfTh[mrow * 72 + ncol] = hh4;
                *(bf16x4*)&kfTl[mrow * 72 + ncol] = ll4;
            }
        }

#pragma unroll
        for (int ks = 0; ks < 2; ++ks) {
#pragma unroll
            for (int mf = 0; mf < 2; ++mf) {
                bf16x8 af = *(const bf16x8*)&kfTh[(w * 32 + mf * 16 + lm) * 72 + ks * 32 + lq * 8];
                bf16x8 afl = *(const bf16x8*)&kfTl[(w * 32 + mf * 16 + lm) * 72 + ks * 32 + lq * 8];
#pragma unroll
                for (int ef = 0; ef < 5; ++ef) {
                    bf16x8 bfh = *(const bf16x8*)&vTh[(ef * 16 + lm) * 72 + ks * 32 + lq * 8];
                    bf16x8 bfl = *(const bf16x8*)&vTl[(ef * 16 + lm) * 72 + ks * 32 + lq * 8];
                    acc[mf][ef] = __builtin_amdgcn_mfma_f32_16x16x32_bf16(af,  bfh, acc[mf][ef], 0, 0, 0);
                    acc[mf][ef] = __builtin_amdgcn_mfma_f32_16x16x32_bf16(afl, bfh, acc[mf][ef], 0, 0, 0);
                    acc[mf][ef] = __builtin_amdgcn_mfma_f32_16x16x32_bf16(af,  bfl, acc[mf][ef], 0, 0, 0);
                }
            }
        }
    }

    __syncthreads();
#pragma unroll
    for (int mf = 0; mf < 2; ++mf)
#pragma unroll
        for (int ef = 0; ef < 5; ++ef)
#pragma unroll
            for (int r = 0; r < 4; ++r) {
                int ml = w * 32 + mf * 16 + lq * 4 + r;
                int e  = ef * 16 + lm;
                ctxe[ml * 81 + e] = acc[mf][ef][r];
            }
    __syncthreads();
    const size_t SLICE = (size_t)(B_ * HEADS_) * EPAD * M_;
    const size_t obase = (size_t)slice * SLICE + (size_t)bh * EPAD * M_;
    for (int i = t; i < EPAD * 128; i += 256) {
        int e = i >> 7, ml = i & 127;
        ctxp[obase + (size_t)e * M_ + mh * 128 + ml] = ctxe[ml * 81 + e];
    }
}

// ======================================================================
// Reduce ctx partials over slices -> bf16 hi/lo ctxT[bh][e][m]
// ======================================================================
__global__ __launch_bounds__(256) void ctx_reduce(
    const float* __restrict__ ctxp, __bf16* __restrict__ ctxTh, __bf16* __restrict__ ctxTl)
{
    int idx = blockIdx.x * 256 + threadIdx.x;
    const size_t SLICE = (size_t)(B_ * HEADS_) * EPAD * M_;
    float s = 0.f;
#pragma unroll
    for (int k = 0; k < NSPLIT; ++k) s += ctxp[(size_t)k * SLICE + idx];
    __bf16 hh = (__bf16)s;
    ctxTh[idx] = hh;
    ctxTl[idx] = (__bf16)(s - (float)hh);
}

// ======================================================================
// out via MFMA (R3-verified). grid (N/64, 32).
// ======================================================================
__global__ __launch_bounds__(256) void out_mfma(
    const __bf16* __restrict__ Qh, const __bf16* __restrict__ Ql,
    const __bf16* __restrict__ projH, const __bf16* __restrict__ projL,
    const __bf16* __restrict__ ctxTh, const __bf16* __restrict__ ctxTl,
    __bf16* __restrict__ attnH, __bf16* __restrict__ attnL)
{
    __shared__ alignas(16) __bf16 qfh[4][16][72];
    __shared__ alignas(16) __bf16 qfl[4][16][72];

    const int t    = threadIdx.x;
    const int lane = t & 63;
    const int w    = t >> 6;
    const int lm   = lane & 15;
    const int lq   = lane >> 4;
    const int bh   = blockIdx.y;
    const int b    = bh >> 4, h = bh & 15;
    const int nw   = blockIdx.x * 64 + w * 16;
    const size_t rowbase = (size_t)b * N_ * H_ + (size_t)h * DH_;

    bf16x8 qh_[2], ql_[2];
#pragma unroll
    for (int ks = 0; ks < 2; ++ks) {
        size_t qa = rowbase + (size_t)(nw + lm) * H_ + ks * 32 + lq * 8;
        qh_[ks] = *(const bf16x8*)(Qh + qa);
        ql_[ks] = *(const bf16x8*)(Ql + qa);
    }

    const __bf16* cth = ctxTh + (size_t)bh * EPAD * M_;
    const __bf16* ctl = ctxTl + (size_t)bh * EPAD * M_;

    f32x4 accO[5];
#pragma unroll
    for (int ef = 0; ef < 5; ++ef) accO[ef] = (f32x4){0.f, 0.f, 0.f, 0.f};

    for (int mc = 0; mc < 4; ++mc) {
        const int m0 = mc * 64;
        f32x4 dsh[4];
#pragma unroll
        for (int mf = 0; mf < 4; ++mf) {
            dsh[mf] = (f32x4){0.f, 0.f, 0.f, 0.f};
#pragma unroll
            for (int ks = 0; ks < 2; ++ks) {
                size_t pa = (size_t)(m0 + mf * 16 + lm) * 64 + ks * 32 + lq * 8;
                bf16x8 ph = *(const bf16x8*)(projH + pa);
                bf16x8 pl = *(const bf16x8*)(projL + pa);
                dsh[mf] = __builtin_amdgcn_mfma_f32_16x16x32_bf16(qh_[ks], ph, dsh[mf], 0, 0, 0);
                dsh[mf] = __builtin_amdgcn_mfma_f32_16x16x32_bf16(ql_[ks], ph, dsh[mf], 0, 0, 0);
                dsh[mf] = __builtin_amdgcn_mfma_f32_16x16x32_bf16(qh_[ks], pl, dsh[mf], 0, 0, 0);
            }
        }
#pragma unroll
        for (int mf = 0; mf < 4; ++mf)
#pragma unroll
            for (int r = 0; r < 4; ++r) {
                float qf = RATIO * (__expf(NORMALIZER * dsh[mf][r]) + KEPS);
                __bf16 hh = (__bf16)qf;
                int nloc = lq * 4 + r;
                qfh[w][nloc][mf * 16 + lm] = hh;
                qfl[w][nloc][mf * 16 + lm] = (__bf16)(qf - (float)hh);
            }
#pragma unroll
        for (int ks = 0; ks < 2; ++ks) {
            bf16x8 af  = *(const bf16x8*)&qfh[w][lm][ks * 32 + lq * 8];
            bf16x8 afl = *(const bf16x8*)&qfl[w][lm][ks * 32 + lq * 8];
#pragma unroll
            for (int ef = 0; ef < 5; ++ef) {
                size_t ca = (size_t)(ef * 16 + lm) * M_ + m0 + ks * 32 + lq * 8;
                bf16x8 bfh = *(const bf16x8*)(cth + ca);
                bf16x8 bfl = *(const bf16x8*)(ctl + ca);
                accO[ef] = __builtin_amdgcn_mfma_f32_16x16x32_bf16(af,  bfh, accO[ef], 0, 0, 0);
                accO[ef] = __builtin_amdgcn_mfma_f32_16x16x32_bf16(afl, bfh, accO[ef], 0, 0, 0);
                accO[ef] = __builtin_amdgcn_mfma_f32_16x16x32_bf16(af,  bfl, accO[ef], 0, 0, 0);
            }
        }
    }

    float dinv[4];
#pragma unroll
    for (int r = 0; r < 4; ++r) {
        float den = __shfl(accO[4][r], lane & 48);
        dinv[r] = 1.f / den;
    }
#pragma unroll
    for (int ef = 0; ef < 4; ++ef)
#pragma unroll
        for (int r = 0; r < 4; ++r) {
            float o = accO[ef][r] * dinv[r];
            __bf16 hh = (__bf16)o;
            size_t oa = rowbase + (size_t)(nw + lq * 4 + r) * H_ + ef * 16 + lm;
            attnH[oa] = hh;
            attnL[oa] = (__bf16)(o - (float)hh);
        }
}

// ======================================================================
extern "C" void kernel_launch(void* const* d_in, const int* in_sizes, int n_in,
                              void* d_out, int out_size, void* d_ws, size_t ws_size,
                              hipStream_t stream) {
    const float* hs   = (const float*)d_in[0];
    const float* Wq   = (const float*)d_in[1];
    const float* bq   = (const float*)d_in[2];
    const float* Wk   = (const float*)d_in[3];
    const float* bk   = (const float*)d_in[4];
    const float* Wv   = (const float*)d_in[5];
    const float* bv   = (const float*)d_in[6];
    const float* Wo   = (const float*)d_in[7];
    const float* bo   = (const float*)d_in[8];
    const float* proj = (const float*)d_in[9];
    float* out = (float*)d_out;

    const size_t QSZ  = (size_t)B_ * N_ * H_;             // 8388608
    const size_t WSZ  = (size_t)H_ * H_;                  // 1048576
    const size_t CTXT = (size_t)B_ * HEADS_ * EPAD * M_;  // 655360

    __bf16* Qh  = (__bf16*)d_ws;
    __bf16* Ql  = Qh + QSZ;
    __bf16* Kh  = Ql + QSZ;
    __bf16* Kl  = Kh + QSZ;
    __bf16* Vh  = Kl + QSZ;
    __bf16* Vl  = Vh + QSZ;
    __bf16* hsH = Vl + QSZ;      // aliased as attnH after hs consumed
    __bf16* hsL = hsH + QSZ;     // aliased as attnL
    __bf16* WH  = hsL + QSZ;
    __bf16* WL  = WH + 4 * WSZ;
    __bf16* projH = WL + 4 * WSZ;
    __bf16* projL = projH + (size_t)M_ * DH_;
    __bf16* ctxTh = projL + (size_t)M_ * DH_;
    __bf16* ctxTl = ctxTh + CTXT;
    float*  diag  = (float*)(ctxTl + CTXT);
    float*  parts = diag + (size_t)B_ * HEADS_ * N_;
    float*  stab  = parts + 2048;
    float*  ctxp  = stab + 16;

    __bf16 *WqH = WH, *WkH = WH + WSZ, *WvH = WH + 2*WSZ, *WoH = WH + 3*WSZ;
    __bf16 *WqL = WL, *WkL = WL + WSZ, *WvL = WL + 2*WSZ, *WoL = WL + 3*WSZ;

    const dim3 ggrid(H_ / 128, (B_ * N_) / 128, 1);

    // 0) splits
    split_bf16<<<QSZ / 4 / 256, 256, 0, stream>>>(hs, hsH, hsL);
    split_w<<<dim3(WSZ / 4 / 256, 4), 256, 0, stream>>>(Wq, Wk, Wv, Wo, WH, WL);
    split_bf16<<<(M_ * DH_) / 4 / 256, 256, 0, stream>>>(proj, projH, projL);

    // 1) Q,K,V projections as 3 separate dispatches (diagnostic: lowers the
    //    top-5 duration ceiling so ctx/out/Wo become visible in rocprof)
    gemm_mfma3<true><<<ggrid, 256, 0, stream>>>(hsH, hsL, WqH, WqL, bq, nullptr, Qh, Ql);
    gemm_mfma3<true><<<ggrid, 256, 0, stream>>>(hsH, hsL, WkH, WkL, bk, nullptr, Kh, Kl);
    gemm_mfma3<true><<<ggrid, 256, 0, stream>>>(hsH, hsL, WvH, WvL, bv, nullptr, Vh, Vl);

    // 2) diag + global stabilizer
    diag_kernel<<<2048, 256, 0, stream>>>(Kh, Kl, diag, parts);
    reduce_stab<<<1, 256, 0, stream>>>(parts, stab, 2048);

    // 3) ctx partials (MFMA)
    ctx_mfma<<<dim3(NSPLIT, 2, B_ * HEADS_), 256, 0, stream>>>(
        Kh, Kl, Vh, Vl, projH, projL, diag, stab, ctxp);

    // 4) reduce partials -> bf16 ctxT
    ctx_reduce<<<(B_ * HEADS_ * EPAD * M_) / 256, 256, 0, stream>>>(ctxp, ctxTh, ctxTl);

    // 5) out (MFMA), writes attn bf16 hi/lo (aliases hs buffers)
    out_mfma<<<dim3(N_ / 64, B_ * HEADS_), 256, 0, stream>>>(
        Qh, Ql, projH, projL, ctxTh, ctxTl, hsH, hsL);

    // 6) final projection fp32 out (single dispatch, fused bias)
    gemm_mfma3<false><<<ggrid, 256, 0, stream>>>(hsH, hsL, WoH, WoL, bo, out, nullptr, nullptr);
}